// Round 2
// baseline (1653.032 us; speedup 1.0000x reference)
//
#include <hip/hip_runtime.h>

#define N_    64
#define CIN_  192
#define T_    256
#define V_    25
#define K_    3
#define COUT_ 64
#define OC_   192
#define SS_   5

#define OUT_OFF_A (N_*COUT_*T_*V_)          // 26214400
#define OUT_OFF_G (OUT_OFF_A + K_*V_*V_)    // 26216275

#define TCH   2              // t's per inner chunk
#define HCH   8              // chunks per block -> 16 t's per block
#define NCOLS 50             // TCH*V_
#define NCT   4              // 16-col tiles in GEMM1 (50 -> pad 64)
#define XB_STRIDE 200        // shorts per XB row (192 + 8 pad)
#define YB_STRIDE 104        // shorts per YB row (75 -> pad 96 -> 104)
#define YB_ROWS 128          // TCH*64
#define BUF_SHORTS 13312     // max(64*200=12800, 128*104=13312); x2 buffers = 53248 B
#define NYV  4800            // OC_*V_ : per-n ybar size
#define CPN  (T_/(TCH*HCH))  // 16 chunk-blocks per n
#define NBLK (N_*CPN)        // 1024 fused blocks
#define CHUNK_UNITS ((CIN_/8)*NCOLS)   // 1200 b128 staging units per chunk
#define UPT 5                // ceil(CHUNK_UNITS/256) units per thread

typedef __attribute__((ext_vector_type(8))) short short8;
typedef __attribute__((ext_vector_type(4))) float float4v;

__device__ inline unsigned bf16r(float f) {            // fp32 -> bf16 RNE
    unsigned u = __float_as_uint(f);
    return (u + 0x7fffu + ((u >> 16) & 1u)) >> 16;
}

// ---------- prep: WcB (bf16), A2T (Acat^T, bf16, zero-padded), A passthrough ----
__global__ __launch_bounds__(256) void prep(const float* __restrict__ Wc,
                                            const float* __restrict__ A,
                                            short* __restrict__ WcB,
                                            short* __restrict__ A2T,
                                            float* __restrict__ out) {
    int idx = blockIdx.x * 256 + threadIdx.x;
    if (idx < OC_ * CIN_) WcB[idx] = (short)bf16r(Wc[idx]);
    if (idx < 32 * YB_STRIDE) {           // A2T[w][kk], kk = k*25+v, zeros elsewhere
        int w = idx / YB_STRIDE, kk = idx - w * YB_STRIDE;
        short val = 0;
        if (w < V_ && kk < K_ * V_) {
            int k = kk / V_, v = kk - k * V_;
            val = (short)bf16r(A[k * V_ * V_ + v * V_ + w]);
        }
        A2T[idx] = val;
    }
    if (idx < K_ * V_ * V_) out[OUT_OFF_A + idx] = A[idx];
}

// ---------- fused MFMA, double-buffered + software-pipelined staging -----------
// buf[p] (p=h&1) holds XB(h) then (union) YB(h). While chunk h computes, chunk
// h+1's global loads are issued into registers after B1 (latency hides under
// Ywrite+GEMM2+partials) and land in buf[p^1] at the tail. 3 barriers/chunk.
// Pad-correctness: A2T cols kk in [75,96) are exact zeros, so stale-but-finite
// bytes in YB pad cols contribute 0; one-time zero of U guarantees finiteness.
__global__ __launch_bounds__(256, 3) void fused_mfma(const float* __restrict__ x,
                                                     const short* __restrict__ WcB,
                                                     const float* __restrict__ bc,
                                                     const short* __restrict__ A2T,
                                                     float* __restrict__ out,
                                                     float* __restrict__ part) {
    __shared__ __align__(16) short U[2 * BUF_SHORTS];

    const int tid  = threadIdx.x;
    const int lane = tid & 63;
    const int wv   = tid >> 6;
    const int l15  = lane & 15;
    const int q    = lane >> 4;
    const int n    = blockIdx.x >> 4;
    const int tc   = blockIdx.x & 15;
    const int rt0  = wv * 3;

    // one-time zero: every byte of U is finite forever after
    {
        int4 z = make_int4(0, 0, 0, 0);
        for (int i = tid; i < 2 * BUF_SHORTS / 8; i += 256) ((int4*)U)[i] = z;
    }
    __syncthreads();

    // bias fragments resident (12 VGPR)
    float4v bvec[3];
#pragma unroll
    for (int j = 0; j < 3; ++j)
        bvec[j] = *(const float4v*)(bc + (rt0 + j) * 16 + q * 4);

    float racc[19];
#pragma unroll
    for (int u = 0; u < 19; ++u) racc[u] = 0.f;

    const float* xn = x + (size_t)n * (CIN_ * T_ * V_);
    const int tbase = tc * (TCH * HCH);

    // prologue: stage chunk 0 into buf 0 (synchronous)
    {
        const float* x0 = xn + (size_t)tbase * V_;
        for (int u = tid; u < CHUNK_UNITS; u += 256) {
            int col = u % NCOLS, cg = u / NCOLS;
            const float* xp = x0 + (size_t)cg * 8 * (T_ * V_) + col;
            short8 s;
#pragma unroll
            for (int j = 0; j < 8; ++j)
                s[j] = (short)bf16r(xp[(size_t)j * (T_ * V_)]);
            *(short8*)&U[col * XB_STRIDE + cg * 8] = s;
        }
    }

    for (int h = 0; h < HCH; ++h) {
        const int bs = (h & 1) * BUF_SHORTS;        // current buffer
        const int ob = ((h & 1) ^ 1) * BUF_SHORTS;  // next-chunk buffer
        const int t0 = tbase + h * TCH;
        const bool stage_ok = (h < HCH - 1);

        __syncthreads();   // B0: XB(h) published (prologue or previous tail)

        // ---- GEMM1: acc[j][ct], K=192=6*32; wfrag streamed from L2 per j ----
        float4v acc[3][NCT];
#pragma unroll
        for (int j = 0; j < 3; ++j)
#pragma unroll
            for (int ct = 0; ct < NCT; ++ct) acc[j][ct] = bvec[j];

        short8 wcur[6], wnxt[6];
        {
            const short* wb = WcB + (rt0 * 16 + l15) * CIN_ + q * 8;
#pragma unroll
            for (int ks = 0; ks < 6; ++ks) wcur[ks] = *(const short8*)(wb + ks * 32);
        }
#pragma unroll
        for (int j = 0; j < 3; ++j) {
            if (j < 2) {
                const short* wb = WcB + ((rt0 + j + 1) * 16 + l15) * CIN_ + q * 8;
#pragma unroll
                for (int ks = 0; ks < 6; ++ks) wnxt[ks] = *(const short8*)(wb + ks * 32);
            }
#pragma unroll
            for (int ct = 0; ct < NCT; ++ct) {
                const short* xb = &U[bs + (ct * 16 + l15) * XB_STRIDE + q * 8];
#pragma unroll
                for (int ks = 0; ks < 6; ++ks) {
                    short8 bfrag = *(const short8*)(xb + ks * 32);
                    acc[j][ct] = __builtin_amdgcn_mfma_f32_16x16x32_bf16(
                        wcur[ks], bfrag, acc[j][ct], 0, 0, 0);
                }
            }
            if (j < 2) {
#pragma unroll
                for (int ks = 0; ks < 6; ++ks) wcur[ks] = wnxt[ks];
            }
        }
        __syncthreads();   // B1: XB reads done; buf becomes YB

        // ---- T14: issue next chunk's global loads now (uses: after partials) --
        float tmp[UPT][8];
        const float* x1 = xn + (size_t)(t0 + TCH) * V_;
#pragma unroll
        for (int s = 0; s < UPT; ++s) {
            int u = tid + s * 256;
            if (stage_ok && u < CHUNK_UNITS) {
                int col = u % NCOLS, cg = u / NCOLS;
                const float* xp = x1 + (size_t)cg * 8 * (T_ * V_) + col;
#pragma unroll
                for (int j = 0; j < 8; ++j) tmp[s][j] = xp[(size_t)j * (T_ * V_)];
            }
        }

        // ---- Ywrite: acc -> YB[(tl*64+cc)][k*25+v] (pad cols stay stale) ----
#pragma unroll
        for (int ct = 0; ct < NCT; ++ct) {
            int col = ct * 16 + l15;
            if (col < NCOLS) {
                int tl = col / V_;
                int v  = col - tl * V_;
#pragma unroll
                for (int j = 0; j < 3; ++j) {
                    int obase = (rt0 + j) * 16 + q * 4;
#pragma unroll
                    for (int i = 0; i < 4; ++i) {
                        int o   = obase + i;
                        int row = tl * 64 + (o & 63);
                        int cY  = (o >> 6) * V_ + v;
                        U[bs + row * YB_STRIDE + cY] = (short)bf16r(acc[j][ct][i]);
                    }
                }
            }
        }
        __syncthreads();   // B2: YB published

        // ---- GEMM2: Out[(t,cc)=128][w pad 32] = Ycat[128][pad96] @ Acat ----
        short8 b2[2][3];
#pragma unroll
        for (int nt = 0; nt < 2; ++nt)
#pragma unroll
            for (int ks = 0; ks < 3; ++ks)
                b2[nt][ks] = *(const short8*)&A2T[(nt * 16 + l15) * YB_STRIDE + ks * 32 + q * 8];

        float4v o2[2][2];
#pragma unroll
        for (int mt = 0; mt < 2; ++mt)
#pragma unroll
            for (int nt = 0; nt < 2; ++nt) o2[mt][nt] = (float4v){0.f, 0.f, 0.f, 0.f};

#pragma unroll
        for (int mt = 0; mt < 2; ++mt) {
            int m = (wv * 2 + mt) * 16 + l15;
            const short* yb = &U[bs + m * YB_STRIDE + q * 8];
#pragma unroll
            for (int ks = 0; ks < 3; ++ks) {
                short8 af = *(const short8*)(yb + ks * 32);
#pragma unroll
                for (int nt = 0; nt < 2; ++nt)
                    o2[mt][nt] = __builtin_amdgcn_mfma_f32_16x16x32_bf16(
                        af, b2[nt][ks], o2[mt][nt], 0, 0, 0);
            }
        }

        // store out[n, cc, t0+tl, w]
#pragma unroll
        for (int mt = 0; mt < 2; ++mt) {
#pragma unroll
            for (int nt = 0; nt < 2; ++nt) {
                int w = nt * 16 + l15;
                if (w < V_) {
#pragma unroll
                    for (int i = 0; i < 4; ++i) {
                        int m  = (wv * 2 + mt) * 16 + q * 4 + i;
                        int cc = m & 63, tl = m >> 6;
                        out[((size_t)(n * COUT_ + cc) * T_ + (t0 + tl)) * V_ + w] = o2[mt][nt][i];
                    }
                }
            }
        }

        // ---- y t-partials from YB: racc[u] += sum_tl y[o, tl, v] ----
#pragma unroll
        for (int u = 0; u < 19; ++u) {
            int idx = tid + u * 256;
            if (u < 18 || idx < NYV) {
                int o = idx / V_, v = idx - (idx / V_) * V_;
                int cc = o & 63, k = o >> 6;
                const short* yp = &U[bs + cc * YB_STRIDE + k * V_ + v];
                float s = 0.f;
#pragma unroll
                for (int tl = 0; tl < TCH; ++tl) {
                    unsigned b = (unsigned short)yp[tl * 64 * YB_STRIDE];
                    s += __uint_as_float(b << 16);
                }
                racc[u] += s;
            }
        }

        // ---- convert + write XB(h+1) into the other buffer (published at B0) --
        if (stage_ok) {
#pragma unroll
            for (int s = 0; s < UPT; ++s) {
                int u = tid + s * 256;
                if (u < CHUNK_UNITS) {
                    int col = u % NCOLS, cg = u / NCOLS;
                    short8 sv;
#pragma unroll
                    for (int j = 0; j < 8; ++j) sv[j] = (short)bf16r(tmp[s][j]);
                    *(short8*)&U[ob + col * XB_STRIDE + cg * 8] = sv;
                }
            }
        }
    }

    // flush per-block partials (coalesced)
    float* pb = part + (size_t)blockIdx.x * NYV;
#pragma unroll
    for (int u = 0; u < 19; ++u) {
        int idx = tid + u * 256;
        if (u < 18 || idx < NYV) pb[idx] = racc[u];
    }
}

// ---------- yred: ysum[n, o, v] = (1/T) * sum_tc part[n*CPN+tc][o,v] ------------
__global__ __launch_bounds__(256) void yred(const float* __restrict__ part,
                                            float* __restrict__ ysum) {
    int i = blockIdx.x * 256 + threadIdx.x;
    if (i >= N_ * NYV) return;
    int n = i / NYV;
    int r = i - n * NYV;
    const float* p = part + (size_t)n * CPN * NYV + r;
    float s = 0.f;
#pragma unroll
    for (int tc = 0; tc < CPN; ++tc) s += p[tc * NYV];
    ysum[i] = s * (1.0f / T_);
}

// ---------- e2: x1m/x2m -> sem -> graphs; block = (n, 10 j's x 25 v) ------------
__global__ __launch_bounds__(256) void e2_graphs(const float* __restrict__ ysum,
                                                 const float* __restrict__ W1,
                                                 const float* __restrict__ b1,
                                                 const float* __restrict__ W2,
                                                 const float* __restrict__ b2,
                                                 const int* __restrict__ node_type,
                                                 float* __restrict__ out) {
    __shared__ float s1[10][V_];
    __shared__ float sem[10];
    const int tid = threadIdx.x;
    const int n  = blockIdx.x >> 5;
    const int jc = blockIdx.x & 31;
    const int jl = tid / V_;
    const int v  = tid - jl * V_;
    const int j  = jc * 10 + jl;
    float x2 = 0.f;
    if (jl < 10) {
        const float* yb = ysum + (size_t)n * NYV + v;
        const float* w1 = W1 + j * OC_;
        const float* w2 = W2 + j * OC_;
        float a1 = b1[j], a2 = b2[j];
        for (int o = 0; o < OC_; ++o) {
            float yv = yb[o * V_];
            a1 += w1[o] * yv;
            a2 += w2[o] * yv;
        }
        s1[jl][v] = a1;
        x2 = a2;
    }
    __syncthreads();
    if (tid < 10) {
        int s = (jc * 10 + tid) >> 6;   // semantic index = j / 64
        float sum = 0.f, cnt = 0.f;
        for (int vv = 0; vv < V_; ++vv)
            if (node_type[vv] == s) { sum += s1[tid][vv]; cnt += 1.f; }
        sem[tid] = sum / cnt;
    }
    __syncthreads();
    if (jl < 10)
        out[OUT_OFF_G + (size_t)n * (SS_ * COUT_ * V_) + j * V_ + v] = sem[jl] - x2;
}

extern "C" void kernel_launch(void* const* d_in, const int* in_sizes, int n_in,
                              void* d_out, int out_size, void* d_ws, size_t ws_size,
                              hipStream_t stream) {
    const float* x         = (const float*)d_in[0];
    const float* A         = (const float*)d_in[1];
    const int*   node_type = (const int*)d_in[2];
    const float* Wc        = (const float*)d_in[3];
    const float* bc        = (const float*)d_in[4];
    const float* W1        = (const float*)d_in[5];
    const float* b1        = (const float*)d_in[6];
    const float* W2        = (const float*)d_in[7];
    const float* b2        = (const float*)d_in[8];
    float* out = (float*)d_out;

    float* part = (float*)d_ws;                    // 1024*4800 floats = 19.7 MB
    float* ysum = part + (size_t)NBLK * NYV;       // 307200 floats
    short* WcB  = (short*)(ysum + N_ * NYV);       // 36864 shorts
    short* A2T  = WcB + OC_ * CIN_;                // 3328 shorts

    hipLaunchKernelGGL(prep, dim3((OC_ * CIN_ + 255) / 256), dim3(256), 0, stream,
                       Wc, A, WcB, A2T, out);
    hipLaunchKernelGGL(fused_mfma, dim3(NBLK), dim3(256), 0, stream,
                       x, WcB, bc, A2T, out, part);
    hipLaunchKernelGGL(yred, dim3((N_ * NYV + 255) / 256), dim3(256), 0, stream,
                       part, ysum);
    hipLaunchKernelGGL(e2_graphs, dim3(N_ * 32), dim3(256), 0, stream,
                       ysum, W1, b1, W2, b2, node_type, out);
}

// Round 3
// 930.896 us; speedup vs baseline: 1.7757x; 1.7757x over previous
//
#include <hip/hip_runtime.h>

#define N_    64
#define CIN_  192
#define T_    256
#define V_    25
#define K_    3
#define COUT_ 64
#define OC_   192
#define SS_   5

#define OUT_OFF_A (N_*COUT_*T_*V_)          // 26214400
#define OUT_OFF_G (OUT_OFF_A + K_*V_*V_)    // 26216275

#define TCH   2              // t's per inner chunk
#define HCH   8              // chunks per block -> 16 t's per block
#define NCOLS 50             // TCH*V_
#define NCT   4              // 16-col tiles in GEMM1 (50 -> pad 64)
#define XB_STRIDE 200        // shorts per XB row (192 + 8 pad); 400B -> 4-bank row rotation
#define XB_ROWS 64           // NCT*16 (rows 50..63 stay zero from init)
#define YB_STRIDE 104        // shorts per YB row (75 -> pad 96 -> 104)
#define YB_ROWS 128          // TCH*64
#define YB_OFF  (XB_ROWS*XB_STRIDE)          // 12800 shorts
#define U_SHORTS (YB_OFF + YB_ROWS*YB_STRIDE) // 26112 shorts = 52224 B -> 3 blocks/CU
#define NYV  4800            // OC_*V_ : per-n ybar size
#define CPN  (T_/(TCH*HCH))  // 16 chunk-blocks per n
#define NBLK (N_*CPN)        // 1024 fused blocks
#define SUNITS (25*(CIN_/8)) // 600 staging units per chunk (col-pair x 8-channel group)

typedef __attribute__((ext_vector_type(8))) short short8;
typedef __attribute__((ext_vector_type(4))) float float4v;

__device__ inline unsigned bf16r(float f) {            // fp32 -> bf16 RNE
    unsigned u = __float_as_uint(f);
    return (u + 0x7fffu + ((u >> 16) & 1u)) >> 16;
}

// ---------- prep: WcB (bf16), A2T (Acat^T, bf16, zero-padded), A passthrough ----
__global__ __launch_bounds__(256) void prep(const float* __restrict__ Wc,
                                            const float* __restrict__ A,
                                            short* __restrict__ WcB,
                                            short* __restrict__ A2T,
                                            float* __restrict__ out) {
    int idx = blockIdx.x * 256 + threadIdx.x;
    if (idx < OC_ * CIN_) WcB[idx] = (short)bf16r(Wc[idx]);
    if (idx < 32 * YB_STRIDE) {           // A2T[w][kk], kk = k*25+v, zeros elsewhere
        int w = idx / YB_STRIDE, kk = idx - w * YB_STRIDE;
        short val = 0;
        if (w < V_ && kk < K_ * V_) {
            int k = kk / V_, v = kk - k * V_;
            val = (short)bf16r(A[k * V_ * V_ + v * V_ + w]);
        }
        A2T[idx] = val;
    }
    if (idx < K_ * V_ * V_) out[OUT_OFF_A + idx] = A[idx];
}

// ---------- fused MFMA: y = Wc@x+bc, out = Ycat@Acat, + per-block y t-partials --
// Separate XB / YB LDS regions (52224 B -> 3 blocks/CU). No register-resident
// staging state across phases (round-2 spill lesson). Staging uses 8 independent
// float2 loads per unit -> 2 ds_write_b128 (2.3 latency rounds per chunk).
// Pad-correctness: A2T cols kk in [75,96) are exact zeros and XB rows 50..63 /
// YB pad cols only ever hold the one-time zero init or finite bf16.
__global__ __launch_bounds__(256, 3) void fused_mfma(const float* __restrict__ x,
                                                     const short* __restrict__ WcB,
                                                     const float* __restrict__ bc,
                                                     const short* __restrict__ A2T,
                                                     float* __restrict__ out,
                                                     float* __restrict__ part) {
    __shared__ __align__(16) short U[U_SHORTS];

    const int tid  = threadIdx.x;
    const int lane = tid & 63;
    const int wv   = tid >> 6;
    const int l15  = lane & 15;
    const int q    = lane >> 4;
    const int n    = blockIdx.x >> 4;
    const int tc   = blockIdx.x & 15;
    const int rt0  = wv * 3;

    // one-time zero: every byte of U is finite forever after; XB rows 50..63 and
    // YB pad columns keep these zeros for the whole kernel.
    {
        int4 z = make_int4(0, 0, 0, 0);
        for (int i = tid; i < U_SHORTS / 8; i += 256) ((int4*)U)[i] = z;
    }
    __syncthreads();

    // bias fragments resident (12 VGPR)
    float4v bvec[3];
#pragma unroll
    for (int j = 0; j < 3; ++j)
        bvec[j] = *(const float4v*)(bc + (rt0 + j) * 16 + q * 4);

    float racc[19];
#pragma unroll
    for (int u = 0; u < 19; ++u) racc[u] = 0.f;

    const float* xn = x + (size_t)n * (CIN_ * T_ * V_);
    const int tbase = tc * (TCH * HCH);

    for (int h = 0; h < HCH; ++h) {
        const int t0 = tbase + h * TCH;   // always even -> float2 offsets 8B-aligned

        // ---- stage XB: unit = (col-pair, 8-channel group) ----
        // XB(h) overwrite is safe: all waves passed B1(h-1) (XB reads done).
        for (int u = tid; u < SUNITS; u += 256) {
            int col2 = u % 25, cg = u / 25;
            const float* xp = xn + (size_t)(cg * 8) * (T_ * V_) + t0 * V_ + col2 * 2;
            float2 f[8];
#pragma unroll
            for (int j = 0; j < 8; ++j)
                f[j] = *(const float2*)(xp + (size_t)j * (T_ * V_));
            short8 a, b;
#pragma unroll
            for (int j = 0; j < 8; ++j) {
                a[j] = (short)bf16r(f[j].x);
                b[j] = (short)bf16r(f[j].y);
            }
            *(short8*)&U[(col2 * 2 + 0) * XB_STRIDE + cg * 8] = a;
            *(short8*)&U[(col2 * 2 + 1) * XB_STRIDE + cg * 8] = b;
        }
        __syncthreads();   // B0: XB(h) published; also fences YB(h-1) readers

        // ---- GEMM1: acc[j][ct], K=192=6*32; wfrag streamed from L2 per j ----
        float4v acc[3][NCT];
#pragma unroll
        for (int j = 0; j < 3; ++j)
#pragma unroll
            for (int ct = 0; ct < NCT; ++ct) acc[j][ct] = bvec[j];

        short8 wcur[6], wnxt[6];
        {
            const short* wb = WcB + (rt0 * 16 + l15) * CIN_ + q * 8;
#pragma unroll
            for (int ks = 0; ks < 6; ++ks) wcur[ks] = *(const short8*)(wb + ks * 32);
        }
#pragma unroll
        for (int j = 0; j < 3; ++j) {
            if (j < 2) {
                const short* wb = WcB + ((rt0 + j + 1) * 16 + l15) * CIN_ + q * 8;
#pragma unroll
                for (int ks = 0; ks < 6; ++ks) wnxt[ks] = *(const short8*)(wb + ks * 32);
            }
#pragma unroll
            for (int ct = 0; ct < NCT; ++ct) {
                const short* xb = &U[(ct * 16 + l15) * XB_STRIDE + q * 8];
#pragma unroll
                for (int ks = 0; ks < 6; ++ks) {
                    short8 bfrag = *(const short8*)(xb + ks * 32);
                    acc[j][ct] = __builtin_amdgcn_mfma_f32_16x16x32_bf16(
                        wcur[ks], bfrag, acc[j][ct], 0, 0, 0);
                }
            }
            if (j < 2) {
#pragma unroll
                for (int ks = 0; ks < 6; ++ks) wcur[ks] = wnxt[ks];
            }
        }
        __syncthreads();   // B1: XB reads done (next chunk may overwrite XB)

        // ---- Ywrite: acc -> YB[(tl*64+cc)][k*25+v] (pad cols stay zero) ----
#pragma unroll
        for (int ct = 0; ct < NCT; ++ct) {
            int col = ct * 16 + l15;
            if (col < NCOLS) {
                int tl = col / V_;
                int v  = col - tl * V_;
#pragma unroll
                for (int j = 0; j < 3; ++j) {
                    int obase = (rt0 + j) * 16 + q * 4;
#pragma unroll
                    for (int i = 0; i < 4; ++i) {
                        int o   = obase + i;
                        int row = tl * 64 + (o & 63);
                        int cY  = (o >> 6) * V_ + v;
                        U[YB_OFF + row * YB_STRIDE + cY] = (short)bf16r(acc[j][ct][i]);
                    }
                }
            }
        }
        __syncthreads();   // B2: YB published

        // ---- GEMM2: Out[(t,cc)=128][w pad 32] = Ycat[128][pad96] @ Acat ----
        short8 b2[2][3];
#pragma unroll
        for (int nt = 0; nt < 2; ++nt)
#pragma unroll
            for (int ks = 0; ks < 3; ++ks)
                b2[nt][ks] = *(const short8*)&A2T[(nt * 16 + l15) * YB_STRIDE + ks * 32 + q * 8];

        float4v o2[2][2];
#pragma unroll
        for (int mt = 0; mt < 2; ++mt)
#pragma unroll
            for (int nt = 0; nt < 2; ++nt) o2[mt][nt] = (float4v){0.f, 0.f, 0.f, 0.f};

#pragma unroll
        for (int mt = 0; mt < 2; ++mt) {
            int m = (wv * 2 + mt) * 16 + l15;
            const short* yb = &U[YB_OFF + m * YB_STRIDE + q * 8];
#pragma unroll
            for (int ks = 0; ks < 3; ++ks) {
                short8 af = *(const short8*)(yb + ks * 32);
#pragma unroll
                for (int nt = 0; nt < 2; ++nt)
                    o2[mt][nt] = __builtin_amdgcn_mfma_f32_16x16x32_bf16(
                        af, b2[nt][ks], o2[mt][nt], 0, 0, 0);
            }
        }

        // store out[n, cc, t0+tl, w]
#pragma unroll
        for (int mt = 0; mt < 2; ++mt) {
#pragma unroll
            for (int nt = 0; nt < 2; ++nt) {
                int w = nt * 16 + l15;
                if (w < V_) {
#pragma unroll
                    for (int i = 0; i < 4; ++i) {
                        int m  = (wv * 2 + mt) * 16 + q * 4 + i;
                        int cc = m & 63, tl = m >> 6;
                        out[((size_t)(n * COUT_ + cc) * T_ + (t0 + tl)) * V_ + w] = o2[mt][nt][i];
                    }
                }
            }
        }

        // ---- y t-partials from YB: racc[u] += sum_tl y[o, tl, v] ----
#pragma unroll
        for (int u = 0; u < 19; ++u) {
            int idx = tid + u * 256;
            if (u < 18 || idx < NYV) {
                int o = idx / V_, v = idx - (idx / V_) * V_;
                int cc = o & 63, k = o >> 6;
                const short* yp = &U[YB_OFF + cc * YB_STRIDE + k * V_ + v];
                float s = 0.f;
#pragma unroll
                for (int tl = 0; tl < TCH; ++tl) {
                    unsigned b = (unsigned short)yp[tl * 64 * YB_STRIDE];
                    s += __uint_as_float(b << 16);
                }
                racc[u] += s;
            }
        }
    }

    // flush per-block partials (coalesced)
    float* pb = part + (size_t)blockIdx.x * NYV;
#pragma unroll
    for (int u = 0; u < 19; ++u) {
        int idx = tid + u * 256;
        if (u < 18 || idx < NYV) pb[idx] = racc[u];
    }
}

// ---------- yred: ysum[n, o, v] = (1/T) * sum_tc part[n*CPN+tc][o,v] ------------
__global__ __launch_bounds__(256) void yred(const float* __restrict__ part,
                                            float* __restrict__ ysum) {
    int i = blockIdx.x * 256 + threadIdx.x;
    if (i >= N_ * NYV) return;
    int n = i / NYV;
    int r = i - n * NYV;
    const float* p = part + (size_t)n * CPN * NYV + r;
    float s = 0.f;
#pragma unroll
    for (int tc = 0; tc < CPN; ++tc) s += p[tc * NYV];
    ysum[i] = s * (1.0f / T_);
}

// ---------- e2: x1m/x2m -> sem -> graphs; block = (n, 10 j's x 25 v) ------------
__global__ __launch_bounds__(256) void e2_graphs(const float* __restrict__ ysum,
                                                 const float* __restrict__ W1,
                                                 const float* __restrict__ b1,
                                                 const float* __restrict__ W2,
                                                 const float* __restrict__ b2,
                                                 const int* __restrict__ node_type,
                                                 float* __restrict__ out) {
    __shared__ float s1[10][V_];
    __shared__ float sem[10];
    const int tid = threadIdx.x;
    const int n  = blockIdx.x >> 5;
    const int jc = blockIdx.x & 31;
    const int jl = tid / V_;
    const int v  = tid - jl * V_;
    const int j  = jc * 10 + jl;
    float x2 = 0.f;
    if (jl < 10) {
        const float* yb = ysum + (size_t)n * NYV + v;
        const float* w1 = W1 + j * OC_;
        const float* w2 = W2 + j * OC_;
        float a1 = b1[j], a2 = b2[j];
        for (int o = 0; o < OC_; ++o) {
            float yv = yb[o * V_];
            a1 += w1[o] * yv;
            a2 += w2[o] * yv;
        }
        s1[jl][v] = a1;
        x2 = a2;
    }
    __syncthreads();
    if (tid < 10) {
        int s = (jc * 10 + tid) >> 6;   // semantic index = j / 64
        float sum = 0.f, cnt = 0.f;
        for (int vv = 0; vv < V_; ++vv)
            if (node_type[vv] == s) { sum += s1[tid][vv]; cnt += 1.f; }
        sem[tid] = sum / cnt;
    }
    __syncthreads();
    if (jl < 10)
        out[OUT_OFF_G + (size_t)n * (SS_ * COUT_ * V_) + j * V_ + v] = sem[jl] - x2;
}

extern "C" void kernel_launch(void* const* d_in, const int* in_sizes, int n_in,
                              void* d_out, int out_size, void* d_ws, size_t ws_size,
                              hipStream_t stream) {
    const float* x         = (const float*)d_in[0];
    const float* A         = (const float*)d_in[1];
    const int*   node_type = (const int*)d_in[2];
    const float* Wc        = (const float*)d_in[3];
    const float* bc        = (const float*)d_in[4];
    const float* W1        = (const float*)d_in[5];
    const float* b1        = (const float*)d_in[6];
    const float* W2        = (const float*)d_in[7];
    const float* b2        = (const float*)d_in[8];
    float* out = (float*)d_out;

    float* part = (float*)d_ws;                    // 1024*4800 floats = 19.7 MB
    float* ysum = part + (size_t)NBLK * NYV;       // 307200 floats
    short* WcB  = (short*)(ysum + N_ * NYV);       // 36864 shorts
    short* A2T  = WcB + OC_ * CIN_;                // 3328 shorts

    hipLaunchKernelGGL(prep, dim3((OC_ * CIN_ + 255) / 256), dim3(256), 0, stream,
                       Wc, A, WcB, A2T, out);
    hipLaunchKernelGGL(fused_mfma, dim3(NBLK), dim3(256), 0, stream,
                       x, WcB, bc, A2T, out, part);
    hipLaunchKernelGGL(yred, dim3((N_ * NYV + 255) / 256), dim3(256), 0, stream,
                       part, ysum);
    hipLaunchKernelGGL(e2_graphs, dim3(N_ * 32), dim3(256), 0, stream,
                       ysum, W1, b1, W2, b2, node_type, out);
}

// Round 4
// 636.840 us; speedup vs baseline: 2.5957x; 1.4617x over previous
//
#include <hip/hip_runtime.h>

#define N_    64
#define CIN_  192
#define T_    256
#define V_    25
#define K_    3
#define COUT_ 64
#define OC_   192
#define SS_   5

#define OUT_OFF_A (N_*COUT_*T_*V_)          // 26214400
#define OUT_OFF_G (OUT_OFF_A + K_*V_*V_)    // 26216275

#define TCH   2              // t's per inner chunk
#define HCH   8              // chunks per block -> 16 t's per block
#define NCOLS 50             // TCH*V_
#define NCT   4              // 16-col tiles in GEMM1 (50 -> pad 64)
#define XB_STRIDE 200        // shorts per XB row (192 + 8 pad)
#define XB_ROWS 64           // NCT*16 (rows 50..63 stay zero from init)
#define XB_SH  (XB_ROWS*XB_STRIDE)            // 12800 shorts per buffer
#define YB_STRIDE 104        // shorts per YB row (75 -> pad 96 -> 104)
#define YB_ROWS 128          // TCH*64
#define YB_OFF  (2*XB_SH)                     // 25600 shorts
#define U_SHORTS (YB_OFF + YB_ROWS*YB_STRIDE) // 38912 shorts = 77824 B -> 2 blocks/CU
#define NYV  4800            // OC_*V_ : per-n ybar size
#define CPN  (T_/(TCH*HCH))  // 16 chunk-blocks per n
#define NBLK (N_*CPN)        // 1024 fused blocks
#define SUNITS (25*(CIN_/8)) // 600 staging units per chunk (col-pair x 8-channel group)
#define UPT 3                // ceil(SUNITS/256) units per thread

typedef __attribute__((ext_vector_type(8))) short short8;
typedef __attribute__((ext_vector_type(4))) float float4v;

__device__ inline unsigned bf16r(float f) {            // fp32 -> bf16 RNE
    unsigned u = __float_as_uint(f);
    return (u + 0x7fffu + ((u >> 16) & 1u)) >> 16;
}

// ---------- prep: WcB (bf16), A2T (Acat^T, bf16, zero-padded), A passthrough ----
__global__ __launch_bounds__(256) void prep(const float* __restrict__ Wc,
                                            const float* __restrict__ A,
                                            short* __restrict__ WcB,
                                            short* __restrict__ A2T,
                                            float* __restrict__ out) {
    int idx = blockIdx.x * 256 + threadIdx.x;
    if (idx < OC_ * CIN_) WcB[idx] = (short)bf16r(Wc[idx]);
    if (idx < 32 * YB_STRIDE) {           // A2T[w][kk], kk = k*25+v, zeros elsewhere
        int w = idx / YB_STRIDE, kk = idx - w * YB_STRIDE;
        short val = 0;
        if (w < V_ && kk < K_ * V_) {
            int k = kk / V_, v = kk - k * V_;
            val = (short)bf16r(A[k * V_ * V_ + v * V_ + w]);
        }
        A2T[idx] = val;
    }
    if (idx < K_ * V_ * V_) out[OUT_OFF_A + idx] = A[idx];
}

// ---------- fused MFMA, double-buffered XB + in-wave pipelined staging ---------
// (256,2): proven no-spill envelope (R1). wfrag RESIDENT (R3 lesson: WcB
// streaming thrashes L2 against the x stream). Chunk h+1's global loads issue
// right after B0(h) into 48 regs; convert+ds_write at the chunk tail into the
// other XB buffer. 2 barriers/chunk:
//   B0 (loop top): publishes XB(h) and fences YB(h-1) readers vs Ywrite(h).
//   B1 (after Ywrite): publishes YB(h).
// Stage-writes target buf[(h+1)&1], whose readers (GEMM1(h-1)) finished before
// B1(h-1) < tail(h). Pad-correctness: A2T cols [75,96) are exact zeros; XB rows
// 50..63 / YB pad cols keep the one-time zero init or finite bf16.
__global__ __launch_bounds__(256, 2) void fused_mfma(const float* __restrict__ x,
                                                     const short* __restrict__ WcB,
                                                     const float* __restrict__ bc,
                                                     const short* __restrict__ A2T,
                                                     float* __restrict__ out,
                                                     float* __restrict__ part) {
    __shared__ __align__(16) short U[U_SHORTS];

    const int tid  = threadIdx.x;
    const int lane = tid & 63;
    const int wv   = tid >> 6;
    const int l15  = lane & 15;
    const int q    = lane >> 4;
    const int n    = blockIdx.x >> 4;
    const int tc   = blockIdx.x & 15;
    const int rt0  = wv * 3;

    // one-time zero: every byte of U is finite forever after
    {
        int4 z = make_int4(0, 0, 0, 0);
        for (int i = tid; i < U_SHORTS / 8; i += 256) ((int4*)U)[i] = z;
    }
    __syncthreads();

    // Wc A-fragments resident in registers (72 VGPR): wave wv owns rows [wv*48,+48)
    short8 wfrag[3][6];
    {
        const short* wb = WcB + (rt0 * 16 + l15) * CIN_ + q * 8;
#pragma unroll
        for (int j = 0; j < 3; ++j)
#pragma unroll
            for (int ks = 0; ks < 6; ++ks)
                wfrag[j][ks] = *(const short8*)(wb + j * 16 * CIN_ + ks * 32);
    }
    float4v bvec[3];
#pragma unroll
    for (int j = 0; j < 3; ++j)
        bvec[j] = *(const float4v*)(bc + (rt0 + j) * 16 + q * 4);

    float racc[19];
#pragma unroll
    for (int u = 0; u < 19; ++u) racc[u] = 0.f;

    const float* xn = x + (size_t)n * (CIN_ * T_ * V_);
    const int tbase = tc * (TCH * HCH);

    // prologue: stage chunk 0 into buffer 0 (synchronous)
    for (int u = tid; u < SUNITS; u += 256) {
        int col2 = u % 25, cg = u / 25;
        const float* xp = xn + (size_t)(cg * 8) * (T_ * V_) + tbase * V_ + col2 * 2;
        short8 a, b;
#pragma unroll
        for (int j = 0; j < 8; ++j) {
            float2 f = *(const float2*)(xp + (size_t)j * (T_ * V_));
            a[j] = (short)bf16r(f.x);
            b[j] = (short)bf16r(f.y);
        }
        *(short8*)&U[(col2 * 2 + 0) * XB_STRIDE + cg * 8] = a;
        *(short8*)&U[(col2 * 2 + 1) * XB_STRIDE + cg * 8] = b;
    }

    for (int h = 0; h < HCH; ++h) {
        const int bs = (h & 1) * XB_SH;        // current XB buffer
        const int ob = ((h & 1) ^ 1) * XB_SH;  // next-chunk XB buffer
        const int t0 = tbase + h * TCH;
        const bool stage_ok = (h < HCH - 1);

        __syncthreads();   // B0: XB(h) ready; YB(h-1) readers done

        // ---- issue chunk h+1's global loads NOW (consumed at chunk tail) ----
        float2 tmp[UPT][8];
#pragma unroll
        for (int s = 0; s < UPT; ++s) {
            int u = tid + s * 256;
            if (stage_ok && u < SUNITS) {
                int col2 = u % 25, cg = u / 25;
                const float* xp = xn + (size_t)(cg * 8) * (T_ * V_) + (t0 + TCH) * V_ + col2 * 2;
#pragma unroll
                for (int j = 0; j < 8; ++j)
                    tmp[s][j] = *(const float2*)(xp + (size_t)j * (T_ * V_));
            }
        }

        // ---- GEMM1: acc[j][ct], K=192=6*32, wfrag resident ----
        float4v acc[3][NCT];
#pragma unroll
        for (int j = 0; j < 3; ++j)
#pragma unroll
            for (int ct = 0; ct < NCT; ++ct) acc[j][ct] = bvec[j];

#pragma unroll
        for (int ct = 0; ct < NCT; ++ct) {
            const short* xb = &U[bs + (ct * 16 + l15) * XB_STRIDE + q * 8];
#pragma unroll
            for (int ks = 0; ks < 6; ++ks) {
                short8 bfrag = *(const short8*)(xb + ks * 32);
#pragma unroll
                for (int j = 0; j < 3; ++j)
                    acc[j][ct] = __builtin_amdgcn_mfma_f32_16x16x32_bf16(
                        wfrag[j][ks], bfrag, acc[j][ct], 0, 0, 0);
            }
        }

        // ---- Ywrite: acc -> YB[(tl*64+cc)][k*25+v] (pad cols stay zero) ----
#pragma unroll
        for (int ct = 0; ct < NCT; ++ct) {
            int col = ct * 16 + l15;
            if (col < NCOLS) {
                int tl = col / V_;
                int v  = col - tl * V_;
#pragma unroll
                for (int j = 0; j < 3; ++j) {
                    int obase = (rt0 + j) * 16 + q * 4;
#pragma unroll
                    for (int i = 0; i < 4; ++i) {
                        int o   = obase + i;
                        int row = tl * 64 + (o & 63);
                        int cY  = (o >> 6) * V_ + v;
                        U[YB_OFF + row * YB_STRIDE + cY] = (short)bf16r(acc[j][ct][i]);
                    }
                }
            }
        }
        __syncthreads();   // B1: YB(h) published

        // ---- GEMM2: Out[(t,cc)=128][w pad 32] = Ycat[128][pad96] @ Acat ----
        short8 b2[2][3];
#pragma unroll
        for (int nt = 0; nt < 2; ++nt)
#pragma unroll
            for (int ks = 0; ks < 3; ++ks)
                b2[nt][ks] = *(const short8*)&A2T[(nt * 16 + l15) * YB_STRIDE + ks * 32 + q * 8];

        float4v o2[2][2];
#pragma unroll
        for (int mt = 0; mt < 2; ++mt)
#pragma unroll
            for (int nt = 0; nt < 2; ++nt) o2[mt][nt] = (float4v){0.f, 0.f, 0.f, 0.f};

#pragma unroll
        for (int mt = 0; mt < 2; ++mt) {
            int m = (wv * 2 + mt) * 16 + l15;
            const short* yb = &U[YB_OFF + m * YB_STRIDE + q * 8];
#pragma unroll
            for (int ks = 0; ks < 3; ++ks) {
                short8 af = *(const short8*)(yb + ks * 32);
#pragma unroll
                for (int nt = 0; nt < 2; ++nt)
                    o2[mt][nt] = __builtin_amdgcn_mfma_f32_16x16x32_bf16(
                        af, b2[nt][ks], o2[mt][nt], 0, 0, 0);
            }
        }

        // store out[n, cc, t0+tl, w]
#pragma unroll
        for (int mt = 0; mt < 2; ++mt) {
#pragma unroll
            for (int nt = 0; nt < 2; ++nt) {
                int w = nt * 16 + l15;
                if (w < V_) {
#pragma unroll
                    for (int i = 0; i < 4; ++i) {
                        int m  = (wv * 2 + mt) * 16 + q * 4 + i;
                        int cc = m & 63, tl = m >> 6;
                        out[((size_t)(n * COUT_ + cc) * T_ + (t0 + tl)) * V_ + w] = o2[mt][nt][i];
                    }
                }
            }
        }

        // ---- y t-partials from YB: racc[u] += sum_tl y[o, tl, v] ----
#pragma unroll
        for (int u = 0; u < 19; ++u) {
            int idx = tid + u * 256;
            if (u < 18 || idx < NYV) {
                int o = idx / V_, v = idx - (idx / V_) * V_;
                int cc = o & 63, k = o >> 6;
                const short* yp = &U[YB_OFF + cc * YB_STRIDE + k * V_ + v];
                float s = 0.f;
#pragma unroll
                for (int tl = 0; tl < TCH; ++tl) {
                    unsigned b = (unsigned short)yp[tl * 64 * YB_STRIDE];
                    s += __uint_as_float(b << 16);
                }
                racc[u] += s;
            }
        }

        // ---- chunk tail: convert tmp + publish XB(h+1) into other buffer ----
        if (stage_ok) {
#pragma unroll
            for (int s = 0; s < UPT; ++s) {
                int u = tid + s * 256;
                if (u < SUNITS) {
                    int col2 = u % 25, cg = u / 25;
                    short8 a, b;
#pragma unroll
                    for (int j = 0; j < 8; ++j) {
                        a[j] = (short)bf16r(tmp[s][j].x);
                        b[j] = (short)bf16r(tmp[s][j].y);
                    }
                    *(short8*)&U[ob + (col2 * 2 + 0) * XB_STRIDE + cg * 8] = a;
                    *(short8*)&U[ob + (col2 * 2 + 1) * XB_STRIDE + cg * 8] = b;
                }
            }
        }
    }

    // flush per-block partials (coalesced)
    float* pb = part + (size_t)blockIdx.x * NYV;
#pragma unroll
    for (int u = 0; u < 19; ++u) {
        int idx = tid + u * 256;
        if (u < 18 || idx < NYV) pb[idx] = racc[u];
    }
}

// ---------- yred: ysum[n, o, v] = (1/T) * sum_tc part[n*CPN+tc][o,v] ------------
__global__ __launch_bounds__(256) void yred(const float* __restrict__ part,
                                            float* __restrict__ ysum) {
    int i = blockIdx.x * 256 + threadIdx.x;
    if (i >= N_ * NYV) return;
    int n = i / NYV;
    int r = i - n * NYV;
    const float* p = part + (size_t)n * CPN * NYV + r;
    float s = 0.f;
#pragma unroll
    for (int tc = 0; tc < CPN; ++tc) s += p[tc * NYV];
    ysum[i] = s * (1.0f / T_);
}

// ---------- e2: x1m/x2m -> sem -> graphs; block = (n, 10 j's x 25 v) ------------
__global__ __launch_bounds__(256) void e2_graphs(const float* __restrict__ ysum,
                                                 const float* __restrict__ W1,
                                                 const float* __restrict__ b1,
                                                 const float* __restrict__ W2,
                                                 const float* __restrict__ b2,
                                                 const int* __restrict__ node_type,
                                                 float* __restrict__ out) {
    __shared__ float s1[10][V_];
    __shared__ float sem[10];
    const int tid = threadIdx.x;
    const int n  = blockIdx.x >> 5;
    const int jc = blockIdx.x & 31;
    const int jl = tid / V_;
    const int v  = tid - jl * V_;
    const int j  = jc * 10 + jl;
    float x2 = 0.f;
    if (jl < 10) {
        const float* yb = ysum + (size_t)n * NYV + v;
        const float* w1 = W1 + j * OC_;
        const float* w2 = W2 + j * OC_;
        float a1 = b1[j], a2 = b2[j];
        for (int o = 0; o < OC_; ++o) {
            float yv = yb[o * V_];
            a1 += w1[o] * yv;
            a2 += w2[o] * yv;
        }
        s1[jl][v] = a1;
        x2 = a2;
    }
    __syncthreads();
    if (tid < 10) {
        int s = (jc * 10 + tid) >> 6;   // semantic index = j / 64
        float sum = 0.f, cnt = 0.f;
        for (int vv = 0; vv < V_; ++vv)
            if (node_type[vv] == s) { sum += s1[tid][vv]; cnt += 1.f; }
        sem[tid] = sum / cnt;
    }
    __syncthreads();
    if (jl < 10)
        out[OUT_OFF_G + (size_t)n * (SS_ * COUT_ * V_) + j * V_ + v] = sem[jl] - x2;
}

extern "C" void kernel_launch(void* const* d_in, const int* in_sizes, int n_in,
                              void* d_out, int out_size, void* d_ws, size_t ws_size,
                              hipStream_t stream) {
    const float* x         = (const float*)d_in[0];
    const float* A         = (const float*)d_in[1];
    const int*   node_type = (const int*)d_in[2];
    const float* Wc        = (const float*)d_in[3];
    const float* bc        = (const float*)d_in[4];
    const float* W1        = (const float*)d_in[5];
    const float* b1        = (const float*)d_in[6];
    const float* W2        = (const float*)d_in[7];
    const float* b2        = (const float*)d_in[8];
    float* out = (float*)d_out;

    float* part = (float*)d_ws;                    // 1024*4800 floats = 19.7 MB
    float* ysum = part + (size_t)NBLK * NYV;       // 307200 floats
    short* WcB  = (short*)(ysum + N_ * NYV);       // 36864 shorts
    short* A2T  = WcB + OC_ * CIN_;                // 3328 shorts

    hipLaunchKernelGGL(prep, dim3((OC_ * CIN_ + 255) / 256), dim3(256), 0, stream,
                       Wc, A, WcB, A2T, out);
    hipLaunchKernelGGL(fused_mfma, dim3(NBLK), dim3(256), 0, stream,
                       x, WcB, bc, A2T, out, part);
    hipLaunchKernelGGL(yred, dim3((N_ * NYV + 255) / 256), dim3(256), 0, stream,
                       part, ysum);
    hipLaunchKernelGGL(e2_graphs, dim3(N_ * 32), dim3(256), 0, stream,
                       ysum, W1, b1, W2, b2, node_type, out);
}

// Round 5
// 618.761 us; speedup vs baseline: 2.6715x; 1.0292x over previous
//
#include <hip/hip_runtime.h>

#define N_    64
#define CIN_  192
#define T_    256
#define V_    25
#define K_    3
#define COUT_ 64
#define OC_   192
#define SS_   5

#define OUT_OFF_A (N_*COUT_*T_*V_)          // 26214400
#define OUT_OFF_G (OUT_OFF_A + K_*V_*V_)    // 26216275

#define TCH   2              // t's per inner chunk
#define HCH   16             // chunks per block -> 32 t's per block
#define NCOLS 50             // TCH*V_
#define NCT   4              // 16-col tiles in GEMM1 (50 -> pad 64)
#define XB_STRIDE 200        // shorts per XB row (192 + 8 pad)
#define XB_ROWS 64           // NCT*16 (rows 50..63 stay zero from init)
#define XB_SH  (XB_ROWS*XB_STRIDE)            // 12800 shorts (single buffer)
#define YB_STRIDE 104        // shorts per YB row (75 -> pad 96 -> 104)
#define YB_ROWS 128          // TCH*64
#define YB_OFF  XB_SH
#define U_SHORTS (YB_OFF + YB_ROWS*YB_STRIDE) // 26112 shorts = 52224 B
#define NYV  4800            // OC_*V_ : per-n ybar size
#define CPN  (T_/(TCH*HCH))  // 8 chunk-blocks per n
#define NBLK (N_*CPN)        // 512 fused blocks = exactly 2/CU, one round
#define SUNITS (25*(CIN_/8)) // 600 staging units per chunk (col-pair x 8-ch group)
#define UPT 3                // ceil(SUNITS/256) units per thread

typedef __attribute__((ext_vector_type(8))) short short8;
typedef __attribute__((ext_vector_type(4))) float float4v;

__device__ inline unsigned bf16r(float f) {            // fp32 -> bf16 RNE
    unsigned u = __float_as_uint(f);
    return (u + 0x7fffu + ((u >> 16) & 1u)) >> 16;
}

// ---------- prep: WcB (bf16), A2T (Acat^T, bf16, zero-padded), A copy, ysum=0 --
__global__ __launch_bounds__(256) void prep(const float* __restrict__ Wc,
                                            const float* __restrict__ A,
                                            short* __restrict__ WcB,
                                            short* __restrict__ A2T,
                                            float* __restrict__ ysum,
                                            float* __restrict__ out) {
    int idx = blockIdx.x * 256 + threadIdx.x;
    if (idx < OC_ * CIN_) WcB[idx] = (short)bf16r(Wc[idx]);
    if (idx < 32 * YB_STRIDE) {           // A2T[w][kk], kk = k*25+v, zeros elsewhere
        int w = idx / YB_STRIDE, kk = idx - w * YB_STRIDE;
        short val = 0;
        if (w < V_ && kk < K_ * V_) {
            int k = kk / V_, v = kk - k * V_;
            val = (short)bf16r(A[k * V_ * V_ + v * V_ + w]);
        }
        A2T[idx] = val;
    }
    if (idx < K_ * V_ * V_) out[OUT_OFF_A + idx] = A[idx];
    if (idx < N_ * NYV) ysum[idx] = 0.f;  // atomic accumulation target for fused
}

// ---------- fused MFMA: y = Wc@x+bc, out = Ycat@Acat, ybar sums via atomics ----
// Single XB buffer: XB(h) readers (GEMM1) all complete before B1(h); the tail
// staging write for XB(h+1) happens after B1(h), so no double-buffer is needed
// with this 2-barrier schedule:
//   B0 (loop top): publishes XB(h); fences YB(h-1) readers vs Ywrite(h).
//   B1 (after Ywrite): publishes YB(h); fences XB(h) readers vs tail write.
// Chunk h+1's global loads issue right after B0(h) into 48 regs (T14); convert +
// ds_write at the chunk tail. Pad-correctness: A2T cols [75,96) are exact zeros;
// XB rows 50..63 / YB pad cols keep the one-time zero init or finite bf16.
__global__ __launch_bounds__(256, 2) void fused_mfma(const float* __restrict__ x,
                                                     const short* __restrict__ WcB,
                                                     const float* __restrict__ bc,
                                                     const short* __restrict__ A2T,
                                                     float* __restrict__ out,
                                                     float* __restrict__ ysum) {
    __shared__ __align__(16) short U[U_SHORTS];

    const int tid  = threadIdx.x;
    const int lane = tid & 63;
    const int wv   = tid >> 6;
    const int l15  = lane & 15;
    const int q    = lane >> 4;
    const int n    = blockIdx.x >> 3;
    const int tc   = blockIdx.x & 7;
    const int rt0  = wv * 3;

    // one-time zero: every byte of U is finite forever after
    {
        int4 z = make_int4(0, 0, 0, 0);
        for (int i = tid; i < U_SHORTS / 8; i += 256) ((int4*)U)[i] = z;
    }
    __syncthreads();

    // Wc A-fragments resident in registers (72 VGPR): wave wv owns rows [wv*48,+48)
    short8 wfrag[3][6];
    {
        const short* wb = WcB + (rt0 * 16 + l15) * CIN_ + q * 8;
#pragma unroll
        for (int j = 0; j < 3; ++j)
#pragma unroll
            for (int ks = 0; ks < 6; ++ks)
                wfrag[j][ks] = *(const short8*)(wb + j * 16 * CIN_ + ks * 32);
    }
    float4v bvec[3];
#pragma unroll
    for (int j = 0; j < 3; ++j)
        bvec[j] = *(const float4v*)(bc + (rt0 + j) * 16 + q * 4);

    // GEMM2 B-fragments: loop-invariant, hoisted (24 VGPR)
    short8 b2[2][3];
#pragma unroll
    for (int nt = 0; nt < 2; ++nt)
#pragma unroll
        for (int ks = 0; ks < 3; ++ks)
            b2[nt][ks] = *(const short8*)&A2T[(nt * 16 + l15) * YB_STRIDE + ks * 32 + q * 8];

    float racc[19];
#pragma unroll
    for (int u = 0; u < 19; ++u) racc[u] = 0.f;

    const float* xn = x + (size_t)n * (CIN_ * T_ * V_);
    const int tbase = tc * (TCH * HCH);

    // prologue: stage chunk 0 (synchronous, once per block)
    for (int u = tid; u < SUNITS; u += 256) {
        int col2 = u % 25, cg = u / 25;
        const float* xp = xn + (size_t)(cg * 8) * (T_ * V_) + tbase * V_ + col2 * 2;
        short8 a, b;
#pragma unroll
        for (int j = 0; j < 8; ++j) {
            float2 f = *(const float2*)(xp + (size_t)j * (T_ * V_));
            a[j] = (short)bf16r(f.x);
            b[j] = (short)bf16r(f.y);
        }
        *(short8*)&U[(col2 * 2 + 0) * XB_STRIDE + cg * 8] = a;
        *(short8*)&U[(col2 * 2 + 1) * XB_STRIDE + cg * 8] = b;
    }

    for (int h = 0; h < HCH; ++h) {
        const int t0 = tbase + h * TCH;
        const bool stage_ok = (h < HCH - 1);

        __syncthreads();   // B0: XB(h) ready; YB(h-1) readers done

        // ---- issue chunk h+1's global loads NOW (consumed at chunk tail) ----
        float2 tmp[UPT][8];
#pragma unroll
        for (int s = 0; s < UPT; ++s) {
            int u = tid + s * 256;
            if (stage_ok && u < SUNITS) {
                int col2 = u % 25, cg = u / 25;
                const float* xp = xn + (size_t)(cg * 8) * (T_ * V_) + (t0 + TCH) * V_ + col2 * 2;
#pragma unroll
                for (int j = 0; j < 8; ++j)
                    tmp[s][j] = *(const float2*)(xp + (size_t)j * (T_ * V_));
            }
        }

        // ---- GEMM1: acc[j][ct], K=192=6*32, wfrag resident ----
        float4v acc[3][NCT];
#pragma unroll
        for (int j = 0; j < 3; ++j)
#pragma unroll
            for (int ct = 0; ct < NCT; ++ct) acc[j][ct] = bvec[j];

#pragma unroll
        for (int ct = 0; ct < NCT; ++ct) {
            const short* xb = &U[(ct * 16 + l15) * XB_STRIDE + q * 8];
#pragma unroll
            for (int ks = 0; ks < 6; ++ks) {
                short8 bfrag = *(const short8*)(xb + ks * 32);
#pragma unroll
                for (int j = 0; j < 3; ++j)
                    acc[j][ct] = __builtin_amdgcn_mfma_f32_16x16x32_bf16(
                        wfrag[j][ks], bfrag, acc[j][ct], 0, 0, 0);
            }
        }

        // ---- Ywrite: acc -> YB[(tl*64+cc)][k*25+v] (pad cols stay zero) ----
#pragma unroll
        for (int ct = 0; ct < NCT; ++ct) {
            int col = ct * 16 + l15;
            if (col < NCOLS) {
                int tl = col / V_;
                int v  = col - tl * V_;
#pragma unroll
                for (int j = 0; j < 3; ++j) {
                    int obase = (rt0 + j) * 16 + q * 4;
#pragma unroll
                    for (int i = 0; i < 4; ++i) {
                        int o   = obase + i;
                        int row = tl * 64 + (o & 63);
                        int cY  = (o >> 6) * V_ + v;
                        U[YB_OFF + row * YB_STRIDE + cY] = (short)bf16r(acc[j][ct][i]);
                    }
                }
            }
        }
        __syncthreads();   // B1: YB(h) published; XB(h) readers done

        // ---- GEMM2: Out[(t,cc)=128][w pad 32] = Ycat[128][pad96] @ Acat ----
        float4v o2[2][2];
#pragma unroll
        for (int mt = 0; mt < 2; ++mt)
#pragma unroll
            for (int nt = 0; nt < 2; ++nt) o2[mt][nt] = (float4v){0.f, 0.f, 0.f, 0.f};

#pragma unroll
        for (int mt = 0; mt < 2; ++mt) {
            int m = (wv * 2 + mt) * 16 + l15;
            const short* yb = &U[YB_OFF + m * YB_STRIDE + q * 8];
#pragma unroll
            for (int ks = 0; ks < 3; ++ks) {
                short8 af = *(const short8*)(yb + ks * 32);
#pragma unroll
                for (int nt = 0; nt < 2; ++nt)
                    o2[mt][nt] = __builtin_amdgcn_mfma_f32_16x16x32_bf16(
                        af, b2[nt][ks], o2[mt][nt], 0, 0, 0);
            }
        }

        // store out[n, cc, t0+tl, w]
#pragma unroll
        for (int mt = 0; mt < 2; ++mt) {
#pragma unroll
            for (int nt = 0; nt < 2; ++nt) {
                int w = nt * 16 + l15;
                if (w < V_) {
#pragma unroll
                    for (int i = 0; i < 4; ++i) {
                        int m  = (wv * 2 + mt) * 16 + q * 4 + i;
                        int cc = m & 63, tl = m >> 6;
                        out[((size_t)(n * COUT_ + cc) * T_ + (t0 + tl)) * V_ + w] = o2[mt][nt][i];
                    }
                }
            }
        }

        // ---- y t-partials from YB: racc[u] += sum_tl y[o, tl, v] ----
#pragma unroll
        for (int u = 0; u < 19; ++u) {
            int idx = tid + u * 256;
            if (u < 18 || idx < NYV) {
                int o = idx / V_, v = idx - (idx / V_) * V_;
                int cc = o & 63, k = o >> 6;
                const short* yp = &U[YB_OFF + cc * YB_STRIDE + k * V_ + v];
                float s = 0.f;
#pragma unroll
                for (int tl = 0; tl < TCH; ++tl) {
                    unsigned b = (unsigned short)yp[tl * 64 * YB_STRIDE];
                    s += __uint_as_float(b << 16);
                }
                racc[u] += s;
            }
        }

        // ---- chunk tail: convert tmp + publish XB(h+1) (safe after B1) ----
        if (stage_ok) {
#pragma unroll
            for (int s = 0; s < UPT; ++s) {
                int u = tid + s * 256;
                if (u < SUNITS) {
                    int col2 = u % 25, cg = u / 25;
                    short8 a, b;
#pragma unroll
                    for (int j = 0; j < 8; ++j) {
                        a[j] = (short)bf16r(tmp[s][j].x);
                        b[j] = (short)bf16r(tmp[s][j].y);
                    }
                    *(short8*)&U[(col2 * 2 + 0) * XB_STRIDE + cg * 8] = a;
                    *(short8*)&U[(col2 * 2 + 1) * XB_STRIDE + cg * 8] = b;
                }
            }
        }
    }

    // flush per-block partials: atomic accumulate into ysum[n] (device scope)
    float* yb = ysum + (size_t)n * NYV;
#pragma unroll
    for (int u = 0; u < 19; ++u) {
        int idx = tid + u * 256;
        if (u < 18 || idx < NYV) atomicAdd(&yb[idx], racc[u]);
    }
}

// ---------- e2: x1m/x2m -> sem -> graphs; block = (n, 10 j's x 25 v) ------------
// ysum holds raw sum over t; the 1/T mean-scale is folded in at the end.
__global__ __launch_bounds__(256) void e2_graphs(const float* __restrict__ ysum,
                                                 const float* __restrict__ W1,
                                                 const float* __restrict__ b1,
                                                 const float* __restrict__ W2,
                                                 const float* __restrict__ b2,
                                                 const int* __restrict__ node_type,
                                                 float* __restrict__ out) {
    __shared__ float s1[10][V_];
    __shared__ float sem[10];
    const int tid = threadIdx.x;
    const int n  = blockIdx.x >> 5;
    const int jc = blockIdx.x & 31;
    const int jl = tid / V_;
    const int v  = tid - jl * V_;
    const int j  = jc * 10 + jl;
    float x2 = 0.f;
    if (jl < 10) {
        const float* yb = ysum + (size_t)n * NYV + v;
        const float* w1 = W1 + j * OC_;
        const float* w2 = W2 + j * OC_;
        float a1 = 0.f, a2 = 0.f;
        for (int o = 0; o < OC_; ++o) {
            float yv = yb[o * V_];
            a1 += w1[o] * yv;
            a2 += w2[o] * yv;
        }
        s1[jl][v] = b1[j] + a1 * (1.0f / T_);
        x2 = b2[j] + a2 * (1.0f / T_);
    }
    __syncthreads();
    if (tid < 10) {
        int s = (jc * 10 + tid) >> 6;   // semantic index = j / 64
        float sum = 0.f, cnt = 0.f;
        for (int vv = 0; vv < V_; ++vv)
            if (node_type[vv] == s) { sum += s1[tid][vv]; cnt += 1.f; }
        sem[tid] = sum / cnt;
    }
    __syncthreads();
    if (jl < 10)
        out[OUT_OFF_G + (size_t)n * (SS_ * COUT_ * V_) + j * V_ + v] = sem[jl] - x2;
}

extern "C" void kernel_launch(void* const* d_in, const int* in_sizes, int n_in,
                              void* d_out, int out_size, void* d_ws, size_t ws_size,
                              hipStream_t stream) {
    const float* x         = (const float*)d_in[0];
    const float* A         = (const float*)d_in[1];
    const int*   node_type = (const int*)d_in[2];
    const float* Wc        = (const float*)d_in[3];
    const float* bc        = (const float*)d_in[4];
    const float* W1        = (const float*)d_in[5];
    const float* b1        = (const float*)d_in[6];
    const float* W2        = (const float*)d_in[7];
    const float* b2        = (const float*)d_in[8];
    float* out = (float*)d_out;

    float* ysum = (float*)d_ws;                    // 307200 floats (atomic target)
    short* WcB  = (short*)(ysum + N_ * NYV);       // 36864 shorts
    short* A2T  = WcB + OC_ * CIN_;                // 3328 shorts

    // prep grid must cover ysum zeroing: N_*NYV = 307200 -> 1200 blocks
    hipLaunchKernelGGL(prep, dim3((N_ * NYV + 255) / 256), dim3(256), 0, stream,
                       Wc, A, WcB, A2T, ysum, out);
    hipLaunchKernelGGL(fused_mfma, dim3(NBLK), dim3(256), 0, stream,
                       x, WcB, bc, A2T, out, ysum);
    hipLaunchKernelGGL(e2_graphs, dim3(N_ * 32), dim3(256), 0, stream,
                       ysum, W1, b1, W2, b2, node_type, out);
}

// Round 6
// 570.947 us; speedup vs baseline: 2.8952x; 1.0837x over previous
//
#include <hip/hip_runtime.h>

#define N_    64
#define CIN_  192
#define T_    256
#define V_    25
#define K_    3
#define COUT_ 64
#define OC_   192
#define SS_   5

#define OUT_OFF_A (N_*COUT_*T_*V_)          // 26214400
#define OUT_OFF_G (OUT_OFF_A + K_*V_*V_)    // 26216275

#define TCH   2              // t's per inner chunk
#define HCH   16             // chunks per block -> 32 t's per block
#define NCOLS 50             // TCH*V_
#define NCT   4              // 16-col tiles in GEMM1 (50 -> pad 64)
#define XB_STRIDE 200        // shorts per XB row (192 + 8 pad)
#define XB_ROWS 64           // NCT*16 (rows 50..63 stay zero from init)
#define XB_SH  (XB_ROWS*XB_STRIDE)            // 12800 shorts (single buffer)
#define YB_STRIDE 104        // shorts per YB row (75 -> pad 96 -> 104)
#define YB_ROWS 128          // TCH*64
#define YB_OFF  XB_SH
#define U_SHORTS (YB_OFF + YB_ROWS*YB_STRIDE) // 26112 shorts = 52224 B
#define NYV  4800            // OC_*V_ : per-n ybar size
#define CPN  (T_/(TCH*HCH))  // 8 chunk-blocks per n
#define NBLK (N_*CPN)        // 512 fused blocks = exactly 2/CU, one round
#define SUNITS (25*(CIN_/8)) // 600 staging units per chunk (col-pair x 8-ch group)
#define UPT 3                // ceil(SUNITS/256) units per thread

// Barrier that does NOT drain vmcnt: each wave drains its own LDS ops
// (lgkmcnt(0)) so producer ds_writes are visible after s_barrier, but
// in-flight global loads/stores stay outstanding across the barrier.
// sched_barrier(0) on both sides pins memory ops (rule #18).
#define BAR_LDS() do {                                          \
    __builtin_amdgcn_sched_barrier(0);                          \
    asm volatile("s_waitcnt lgkmcnt(0)" ::: "memory");          \
    __builtin_amdgcn_s_barrier();                               \
    __builtin_amdgcn_sched_barrier(0);                          \
} while (0)

typedef __attribute__((ext_vector_type(8))) short short8;
typedef __attribute__((ext_vector_type(4))) float float4v;

__device__ inline unsigned bf16r(float f) {            // fp32 -> bf16 RNE
    unsigned u = __float_as_uint(f);
    return (u + 0x7fffu + ((u >> 16) & 1u)) >> 16;
}

// ---------- prep: WcB (bf16), A2T (Acat^T, bf16, zero-padded), A copy, ysum=0 --
__global__ __launch_bounds__(256) void prep(const float* __restrict__ Wc,
                                            const float* __restrict__ A,
                                            short* __restrict__ WcB,
                                            short* __restrict__ A2T,
                                            float* __restrict__ ysum,
                                            float* __restrict__ out) {
    int idx = blockIdx.x * 256 + threadIdx.x;
    if (idx < OC_ * CIN_) WcB[idx] = (short)bf16r(Wc[idx]);
    if (idx < 32 * YB_STRIDE) {           // A2T[w][kk], kk = k*25+v, zeros elsewhere
        int w = idx / YB_STRIDE, kk = idx - w * YB_STRIDE;
        short val = 0;
        if (w < V_ && kk < K_ * V_) {
            int k = kk / V_, v = kk - k * V_;
            val = (short)bf16r(A[k * V_ * V_ + v * V_ + w]);
        }
        A2T[idx] = val;
    }
    if (idx < K_ * V_ * V_) out[OUT_OFF_A + idx] = A[idx];
    if (idx < N_ * NYV) ysum[idx] = 0.f;  // atomic accumulation target for fused
}

// ---------- fused MFMA: y = Wc@x+bc, out = Ycat@Acat, ybar sums via atomics ----
// Pipelined staging, FORCED: chunk h+1's 24 global loads issue right after
// B0(h), pinned by sched_barrier(0) so the compiler cannot sink them to their
// consumer (R5 post-mortem: with 128 VGPRs it did exactly that, serializing
// HBM latency into every chunk). b2 is reloaded per chunk (L2-hot 6.6 KB) to
// pay the 48-VGPR tmp bill inside the (256,2) budget.
// Barrier schedule (lgkmcnt-only, vmem stays in flight):
//   B0 (loop top): publishes XB(h) tail-writes; fences YB(h-1) readers.
//   B1 (after Ywrite): publishes YB(h); fences XB(h) readers vs tail write.
// Pad-correctness: A2T cols [75,96) are exact zeros; XB rows 50..63 / YB pad
// cols keep the one-time zero init or finite bf16.
__global__ __launch_bounds__(256, 2) void fused_mfma(const float* __restrict__ x,
                                                     const short* __restrict__ WcB,
                                                     const float* __restrict__ bc,
                                                     const short* __restrict__ A2T,
                                                     float* __restrict__ out,
                                                     float* __restrict__ ysum) {
    __shared__ __align__(16) short U[U_SHORTS];

    const int tid  = threadIdx.x;
    const int lane = tid & 63;
    const int wv   = tid >> 6;
    const int l15  = lane & 15;
    const int q    = lane >> 4;
    const int n    = blockIdx.x >> 3;
    const int tc   = blockIdx.x & 7;
    const int rt0  = wv * 3;

    // one-time zero: every byte of U is finite forever after
    {
        int4 z = make_int4(0, 0, 0, 0);
        for (int i = tid; i < U_SHORTS / 8; i += 256) ((int4*)U)[i] = z;
    }
    __syncthreads();

    // Wc A-fragments resident in registers (72 VGPR): wave wv owns rows [wv*48,+48)
    short8 wfrag[3][6];
    {
        const short* wb = WcB + (rt0 * 16 + l15) * CIN_ + q * 8;
#pragma unroll
        for (int j = 0; j < 3; ++j)
#pragma unroll
            for (int ks = 0; ks < 6; ++ks)
                wfrag[j][ks] = *(const short8*)(wb + j * 16 * CIN_ + ks * 32);
    }
    float4v bvec[3];
#pragma unroll
    for (int j = 0; j < 3; ++j)
        bvec[j] = *(const float4v*)(bc + (rt0 + j) * 16 + q * 4);

    float racc[19];
#pragma unroll
    for (int u = 0; u < 19; ++u) racc[u] = 0.f;

    const float* xn = x + (size_t)n * (CIN_ * T_ * V_);
    const int tbase = tc * (TCH * HCH);

    // prologue: stage chunk 0 (synchronous, once per block)
    for (int u = tid; u < SUNITS; u += 256) {
        int col2 = u % 25, cg = u / 25;
        const float* xp = xn + (size_t)(cg * 8) * (T_ * V_) + tbase * V_ + col2 * 2;
        short8 a, b;
#pragma unroll
        for (int j = 0; j < 8; ++j) {
            float2 f = *(const float2*)(xp + (size_t)j * (T_ * V_));
            a[j] = (short)bf16r(f.x);
            b[j] = (short)bf16r(f.y);
        }
        *(short8*)&U[(col2 * 2 + 0) * XB_STRIDE + cg * 8] = a;
        *(short8*)&U[(col2 * 2 + 1) * XB_STRIDE + cg * 8] = b;
    }

    for (int h = 0; h < HCH; ++h) {
        const int t0 = tbase + h * TCH;
        const bool stage_ok = (h < HCH - 1);

        BAR_LDS();         // B0: XB(h) ready; YB(h-1) readers done

        // ---- prefetch: issue chunk h+1's 24 global loads NOW, pinned ----
        float2 tmp[UPT][8];
        if (stage_ok) {
#pragma unroll
            for (int s = 0; s < UPT; ++s) {
                int u = tid + s * 256;
                if (u < SUNITS) {
                    int col2 = u % 25, cg = u / 25;
                    const float* xp = xn + (size_t)(cg * 8) * (T_ * V_) + (t0 + TCH) * V_ + col2 * 2;
#pragma unroll
                    for (int j = 0; j < 8; ++j)
                        tmp[s][j] = *(const float2*)(xp + (size_t)j * (T_ * V_));
                }
            }
            __builtin_amdgcn_sched_barrier(0);   // loads may not sink past here
        }

        // ---- GEMM1: acc[j][ct], K=192=6*32, wfrag resident ----
        float4v acc[3][NCT];
#pragma unroll
        for (int j = 0; j < 3; ++j)
#pragma unroll
            for (int ct = 0; ct < NCT; ++ct) acc[j][ct] = bvec[j];

#pragma unroll
        for (int ct = 0; ct < NCT; ++ct) {
            const short* xb = &U[(ct * 16 + l15) * XB_STRIDE + q * 8];
#pragma unroll
            for (int ks = 0; ks < 6; ++ks) {
                short8 bfrag = *(const short8*)(xb + ks * 32);
#pragma unroll
                for (int j = 0; j < 3; ++j)
                    acc[j][ct] = __builtin_amdgcn_mfma_f32_16x16x32_bf16(
                        wfrag[j][ks], bfrag, acc[j][ct], 0, 0, 0);
            }
        }

        // ---- Ywrite: acc -> YB[(tl*64+cc)][k*25+v] (pad cols stay zero) ----
#pragma unroll
        for (int ct = 0; ct < NCT; ++ct) {
            int col = ct * 16 + l15;
            if (col < NCOLS) {
                int tl = col / V_;
                int v  = col - tl * V_;
#pragma unroll
                for (int j = 0; j < 3; ++j) {
                    int obase = (rt0 + j) * 16 + q * 4;
#pragma unroll
                    for (int i = 0; i < 4; ++i) {
                        int o   = obase + i;
                        int row = tl * 64 + (o & 63);
                        int cY  = (o >> 6) * V_ + v;
                        U[YB_OFF + row * YB_STRIDE + cY] = (short)bf16r(acc[j][ct][i]);
                    }
                }
            }
        }

        BAR_LDS();         // B1: YB(h) published; XB(h) readers done; vmem flies on

        // ---- GEMM2: Out[(t,cc)=128][w pad 32] = Ycat[128][pad96] @ Acat ----
        // b2 reloaded per chunk (L2-hot; frees 24 regs for the prefetch tmp)
        short8 b2[2][3];
#pragma unroll
        for (int nt = 0; nt < 2; ++nt)
#pragma unroll
            for (int ks = 0; ks < 3; ++ks)
                b2[nt][ks] = *(const short8*)&A2T[(nt * 16 + l15) * YB_STRIDE + ks * 32 + q * 8];

        float4v o2[2][2];
#pragma unroll
        for (int mt = 0; mt < 2; ++mt)
#pragma unroll
            for (int nt = 0; nt < 2; ++nt) o2[mt][nt] = (float4v){0.f, 0.f, 0.f, 0.f};

#pragma unroll
        for (int mt = 0; mt < 2; ++mt) {
            int m = (wv * 2 + mt) * 16 + l15;
            const short* yb = &U[YB_OFF + m * YB_STRIDE + q * 8];
#pragma unroll
            for (int ks = 0; ks < 3; ++ks) {
                short8 af = *(const short8*)(yb + ks * 32);
#pragma unroll
                for (int nt = 0; nt < 2; ++nt)
                    o2[mt][nt] = __builtin_amdgcn_mfma_f32_16x16x32_bf16(
                        af, b2[nt][ks], o2[mt][nt], 0, 0, 0);
            }
        }

        // store out[n, cc, t0+tl, w]
#pragma unroll
        for (int mt = 0; mt < 2; ++mt) {
#pragma unroll
            for (int nt = 0; nt < 2; ++nt) {
                int w = nt * 16 + l15;
                if (w < V_) {
#pragma unroll
                    for (int i = 0; i < 4; ++i) {
                        int m  = (wv * 2 + mt) * 16 + q * 4 + i;
                        int cc = m & 63, tl = m >> 6;
                        out[((size_t)(n * COUT_ + cc) * T_ + (t0 + tl)) * V_ + w] = o2[mt][nt][i];
                    }
                }
            }
        }

        // ---- y t-partials from YB: racc[u] += sum_tl y[o, tl, v] ----
#pragma unroll
        for (int u = 0; u < 19; ++u) {
            int idx = tid + u * 256;
            if (u < 18 || idx < NYV) {
                int o = idx / V_, v = idx - (idx / V_) * V_;
                int cc = o & 63, k = o >> 6;
                const short* yp = &U[YB_OFF + cc * YB_STRIDE + k * V_ + v];
                float s = 0.f;
#pragma unroll
                for (int tl = 0; tl < TCH; ++tl) {
                    unsigned b = (unsigned short)yp[tl * 64 * YB_STRIDE];
                    s += __uint_as_float(b << 16);
                }
                racc[u] += s;
            }
        }

        // ---- chunk tail: convert tmp + publish XB(h+1) (safe after B1) ----
        if (stage_ok) {
#pragma unroll
            for (int s = 0; s < UPT; ++s) {
                int u = tid + s * 256;
                if (u < SUNITS) {
                    int col2 = u % 25, cg = u / 25;
                    short8 a, b;
#pragma unroll
                    for (int j = 0; j < 8; ++j) {
                        a[j] = (short)bf16r(tmp[s][j].x);
                        b[j] = (short)bf16r(tmp[s][j].y);
                    }
                    *(short8*)&U[(col2 * 2 + 0) * XB_STRIDE + cg * 8] = a;
                    *(short8*)&U[(col2 * 2 + 1) * XB_STRIDE + cg * 8] = b;
                }
            }
        }
    }

    // flush per-block partials: atomic accumulate into ysum[n] (device scope)
    float* yb = ysum + (size_t)n * NYV;
#pragma unroll
    for (int u = 0; u < 19; ++u) {
        int idx = tid + u * 256;
        if (u < 18 || idx < NYV) atomicAdd(&yb[idx], racc[u]);
    }
}

// ---------- e2: x1m/x2m -> sem -> graphs; block = (n, 10 j's x 25 v) ------------
// ysum holds raw sum over t; the 1/T mean-scale is folded in at the end.
__global__ __launch_bounds__(256) void e2_graphs(const float* __restrict__ ysum,
                                                 const float* __restrict__ W1,
                                                 const float* __restrict__ b1,
                                                 const float* __restrict__ W2,
                                                 const float* __restrict__ b2,
                                                 const int* __restrict__ node_type,
                                                 float* __restrict__ out) {
    __shared__ float s1[10][V_];
    __shared__ float sem[10];
    const int tid = threadIdx.x;
    const int n  = blockIdx.x >> 5;
    const int jc = blockIdx.x & 31;
    const int jl = tid / V_;
    const int v  = tid - jl * V_;
    const int j  = jc * 10 + jl;
    float x2 = 0.f;
    if (jl < 10) {
        const float* yb = ysum + (size_t)n * NYV + v;
        const float* w1 = W1 + j * OC_;
        const float* w2 = W2 + j * OC_;
        float a1 = 0.f, a2 = 0.f;
        for (int o = 0; o < OC_; ++o) {
            float yv = yb[o * V_];
            a1 += w1[o] * yv;
            a2 += w2[o] * yv;
        }
        s1[jl][v] = b1[j] + a1 * (1.0f / T_);
        x2 = b2[j] + a2 * (1.0f / T_);
    }
    __syncthreads();
    if (tid < 10) {
        int s = (jc * 10 + tid) >> 6;   // semantic index = j / 64
        float sum = 0.f, cnt = 0.f;
        for (int vv = 0; vv < V_; ++vv)
            if (node_type[vv] == s) { sum += s1[tid][vv]; cnt += 1.f; }
        sem[tid] = sum / cnt;
    }
    __syncthreads();
    if (jl < 10)
        out[OUT_OFF_G + (size_t)n * (SS_ * COUT_ * V_) + j * V_ + v] = sem[jl] - x2;
}

extern "C" void kernel_launch(void* const* d_in, const int* in_sizes, int n_in,
                              void* d_out, int out_size, void* d_ws, size_t ws_size,
                              hipStream_t stream) {
    const float* x         = (const float*)d_in[0];
    const float* A         = (const float*)d_in[1];
    const int*   node_type = (const int*)d_in[2];
    const float* Wc        = (const float*)d_in[3];
    const float* bc        = (const float*)d_in[4];
    const float* W1        = (const float*)d_in[5];
    const float* b1        = (const float*)d_in[6];
    const float* W2        = (const float*)d_in[7];
    const float* b2        = (const float*)d_in[8];
    float* out = (float*)d_out;

    float* ysum = (float*)d_ws;                    // 307200 floats (atomic target)
    short* WcB  = (short*)(ysum + N_ * NYV);       // 36864 shorts
    short* A2T  = WcB + OC_ * CIN_;                // 3328 shorts

    // prep grid must cover ysum zeroing: N_*NYV = 307200 -> 1200 blocks
    hipLaunchKernelGGL(prep, dim3((N_ * NYV + 255) / 256), dim3(256), 0, stream,
                       Wc, A, WcB, A2T, ysum, out);
    hipLaunchKernelGGL(fused_mfma, dim3(NBLK), dim3(256), 0, stream,
                       x, WcB, bc, A2T, out, ysum);
    hipLaunchKernelGGL(e2_graphs, dim3(N_ * 32), dim3(256), 0, stream,
                       ysum, W1, b1, W2, b2, node_type, out);
}